// Round 1
// baseline (141.674 us; speedup 1.0000x reference)
//
#include <hip/hip_runtime.h>
#include <hip/hip_bf16.h>

#define NUM_CLASSES 6
#define NUM_SUBJECTS 16
#define NUM_PAIRS (NUM_CLASSES * NUM_SUBJECTS)   // 96
#define MARGIN 1.0f
#define EPS 1e-6f

// ---------------- ws layout (bytes) ----------------
// [0)      int   min1[96]
// [384)    int   min2[96]
// [768)    int   cntPos[96]
// [1152)   int   cntSbj[16]
// [1216)   u64   best[96]          (packed: sortable_key(d2)<<32 | idx)
// [1984)   float a2[96]
// [2368)   float anchors[96*256]
// total ~100 KB

__device__ __forceinline__ float wredsum(float v) {
#pragma unroll
    for (int m = 32; m >= 1; m >>= 1) v += __shfl_xor(v, m, 64);
    return v;
}

__device__ __forceinline__ unsigned int fkey(float f) {
    unsigned int b = __float_as_uint(f);
    return (b & 0x80000000u) ? ~b : (b | 0x80000000u);
}

__global__ void k_init(int* min1, int* min2, int* cntPos, int* cntSbj,
                       unsigned long long* best, float* a2) {
    int t = threadIdx.x;
    if (t < NUM_PAIRS) {
        min1[t] = 0x7fffffff;
        min2[t] = 0x7fffffff;
        cntPos[t] = 0;
        best[t] = ~0ull;
        a2[t] = 0.f;
    }
    if (t < NUM_SUBJECTS) cntSbj[t] = 0;
}

__global__ void k_pass1(const int* __restrict__ labels, const int* __restrict__ sbj,
                        int* min1, int* cntPos, int* cntSbj, int B) {
    __shared__ int lmin[NUM_PAIRS];
    __shared__ int lcp[NUM_PAIRS];
    __shared__ int lcs[NUM_SUBJECTS];
    for (int t = threadIdx.x; t < NUM_PAIRS; t += blockDim.x) { lmin[t] = 0x7fffffff; lcp[t] = 0; }
    if (threadIdx.x < NUM_SUBJECTS) lcs[threadIdx.x] = 0;
    __syncthreads();
    int i = blockIdx.x * blockDim.x + threadIdx.x;
    if (i < B) {
        int s = sbj[i], c = labels[i];
        int p = s * NUM_CLASSES + c;
        atomicMin(&lmin[p], i);
        atomicAdd(&lcp[p], 1);
        atomicAdd(&lcs[s], 1);
    }
    __syncthreads();
    for (int t = threadIdx.x; t < NUM_PAIRS; t += blockDim.x) {
        if (lmin[t] != 0x7fffffff) atomicMin(&min1[t], lmin[t]);
        if (lcp[t]) atomicAdd(&cntPos[t], lcp[t]);
    }
    if (threadIdx.x < NUM_SUBJECTS && lcs[threadIdx.x]) atomicAdd(&cntSbj[threadIdx.x], lcs[threadIdx.x]);
}

__global__ void k_pass2(const int* __restrict__ labels, const int* __restrict__ sbj,
                        const int* __restrict__ min1, int* min2, int B) {
    __shared__ int lmin[NUM_PAIRS];
    for (int t = threadIdx.x; t < NUM_PAIRS; t += blockDim.x) lmin[t] = 0x7fffffff;
    __syncthreads();
    int i = blockIdx.x * blockDim.x + threadIdx.x;
    if (i < B) {
        int s = sbj[i], c = labels[i];
        int p = s * NUM_CLASSES + c;
        if (i != min1[p]) atomicMin(&lmin[p], i);
    }
    __syncthreads();
    for (int t = threadIdx.x; t < NUM_PAIRS; t += blockDim.x)
        if (lmin[t] != 0x7fffffff) atomicMin(&min2[t], lmin[t]);
}

__global__ void k_gather(const float4* __restrict__ emb4, const int* __restrict__ min1,
                         float4* anchors4, float* a2, int B) {
    int p = blockIdx.x;          // 96 blocks
    int lane = threadIdx.x;      // 64 threads
    int idx = min1[p];
    if (idx < 0 || idx >= B) idx = 0;
    float4 v = emb4[(size_t)idx * 64 + lane];
    anchors4[(size_t)p * 64 + lane] = v;
    float t = v.x * v.x + v.y * v.y + v.z * v.z + v.w * v.w;
    t = wredsum(t);
    if (lane == 0) a2[p] = t;
}

__global__ __launch_bounds__(1024) void k_mine(const float4* __restrict__ emb4,
                                               const int* __restrict__ labels,
                                               const int* __restrict__ sbj,
                                               const float4* __restrict__ anchors4,
                                               const float* __restrict__ a2,
                                               unsigned long long* gbest, int B) {
    __shared__ unsigned long long lbest[NUM_PAIRS];
    for (int t = threadIdx.x; t < NUM_PAIRS; t += blockDim.x) lbest[t] = ~0ull;
    __syncthreads();

    const int lane = threadIdx.x & 63;
    const int wave = (int)((blockIdx.x * blockDim.x + threadIdx.x) >> 6);
    const int nwaves = (int)((gridDim.x * blockDim.x) >> 6);

    for (int i = wave; i < B; i += nwaves) {
        int s = sbj[i];
        int ci = labels[i];
        float4 v = emb4[(size_t)i * 64 + lane];
        float e2 = v.x * v.x + v.y * v.y + v.z * v.z + v.w * v.w;
        float dc[NUM_CLASSES];
        const float4* abase = anchors4 + (size_t)s * NUM_CLASSES * 64;
#pragma unroll
        for (int c = 0; c < NUM_CLASSES; ++c) {
            float4 a = abase[(size_t)c * 64 + lane];
            dc[c] = a.x * v.x + a.y * v.y + a.z * v.z + a.w * v.w;
        }
        e2 = wredsum(e2);
#pragma unroll
        for (int c = 0; c < NUM_CLASSES; ++c) dc[c] = wredsum(dc[c]);
        if (lane == 0) {
            int pbase = s * NUM_CLASSES;
#pragma unroll
            for (int c = 0; c < NUM_CLASSES; ++c) {
                if (c == ci) continue;
                float d2 = a2[pbase + c] + e2 - 2.0f * dc[c];
                unsigned long long packed =
                    ((unsigned long long)fkey(d2) << 32) | (unsigned int)i;
                atomicMin(&lbest[pbase + c], packed);
            }
        }
    }
    __syncthreads();
    for (int t = threadIdx.x; t < NUM_PAIRS; t += blockDim.x)
        if (lbest[t] != ~0ull) atomicMin(&gbest[t], lbest[t]);
}

__global__ __launch_bounds__(1024) void k_finalize(const float4* __restrict__ emb4,
                                                   const int* __restrict__ min1,
                                                   const int* __restrict__ min2,
                                                   const int* __restrict__ cntPos,
                                                   const int* __restrict__ cntSbj,
                                                   const unsigned long long* __restrict__ best,
                                                   float* out, int B) {
    __shared__ float vals[NUM_PAIRS];
    __shared__ int vld[NUM_PAIRS];
    int wave = threadIdx.x >> 6;
    int lane = threadIdx.x & 63;
    for (int p = wave; p < NUM_PAIRS; p += (blockDim.x >> 6)) {
        int s = p / NUM_CLASSES;
        int ai = min1[p], pi = min2[p];
        int npos = cntPos[p];
        int nneg = cntSbj[s] - npos;
        unsigned long long bb = best[p];
        int ni = (int)(bb & 0xffffffffu);
        bool ok = (npos >= 2) && (nneg >= 1) && (bb != ~0ull);
        if (ai < 0 || ai >= B) ai = 0;
        if (pi < 0 || pi >= B) pi = 0;
        if (ni < 0 || ni >= B) ni = 0;
        float4 a = emb4[(size_t)ai * 64 + lane];
        float4 pp = emb4[(size_t)pi * 64 + lane];
        float4 nn = emb4[(size_t)ni * 64 + lane];
        float dap = 0.f, dan = 0.f, t;
        t = a.x - pp.x + EPS; dap += t * t;
        t = a.y - pp.y + EPS; dap += t * t;
        t = a.z - pp.z + EPS; dap += t * t;
        t = a.w - pp.w + EPS; dap += t * t;
        t = a.x - nn.x + EPS; dan += t * t;
        t = a.y - nn.y + EPS; dan += t * t;
        t = a.z - nn.z + EPS; dan += t * t;
        t = a.w - nn.w + EPS; dan += t * t;
        dap = wredsum(dap);
        dan = wredsum(dan);
        if (lane == 0) {
            float lv = sqrtf(dap) - sqrtf(dan) + MARGIN;
            vals[p] = ok ? fmaxf(lv, 0.f) : 0.f;
            vld[p] = ok ? 1 : 0;
        }
    }
    __syncthreads();
    if (threadIdx.x == 0) {
        float sum = 0.f;
        int cnt = 0;
        for (int p = 0; p < NUM_PAIRS; ++p) { sum += vals[p]; cnt += vld[p]; }
        out[0] = (cnt > 0) ? (sum / (float)cnt) : 0.f;
    }
}

extern "C" void kernel_launch(void* const* d_in, const int* in_sizes, int n_in,
                              void* d_out, int out_size, void* d_ws, size_t ws_size,
                              hipStream_t stream) {
    const float* emb = (const float*)d_in[0];
    const int* labels = (const int*)d_in[1];
    const int* sbj = (const int*)d_in[2];
    float* out = (float*)d_out;
    const int B = in_sizes[1];           // 131072
    const float4* emb4 = (const float4*)emb;

    char* ws = (char*)d_ws;
    int* min1 = (int*)(ws + 0);
    int* min2 = (int*)(ws + 384);
    int* cntPos = (int*)(ws + 768);
    int* cntSbj = (int*)(ws + 1152);
    unsigned long long* best = (unsigned long long*)(ws + 1216);
    float* a2 = (float*)(ws + 1984);
    float4* anchors4 = (float4*)(ws + 2368);

    k_init<<<1, 128, 0, stream>>>(min1, min2, cntPos, cntSbj, best, a2);

    int blk = 256;
    int grd = (B + blk - 1) / blk;
    k_pass1<<<grd, blk, 0, stream>>>(labels, sbj, min1, cntPos, cntSbj, B);
    k_pass2<<<grd, blk, 0, stream>>>(labels, sbj, min1, min2, B);

    k_gather<<<NUM_PAIRS, 64, 0, stream>>>(emb4, min1, anchors4, a2, B);

    k_mine<<<512, 1024, 0, stream>>>(emb4, labels, sbj, anchors4, a2, best, B);

    k_finalize<<<1, 1024, 0, stream>>>(emb4, min1, min2, cntPos, cntSbj, best, out, B);
}